// Round 8
// baseline (398.639 us; speedup 1.0000x reference)
//
#include <hip/hip_runtime.h>
#include <hip/hip_cooperative_groups.h>

namespace cg = cooperative_groups;

// RoundRobinGate: output = (0.0 scalar, one-hot [2,4096,16,512] f32, same tensor as
// bool->f32). Fully input-independent: 537 MB of zeros + 16,384 ones. Pure store-BW.
//
// Single cooperative kernel:
//   phase 1: pure zero-fill. 2048 persistent blocks x 256 threads; each block owns a
//            CONTIGUOUS 256 KB region (16384 quads), written as 64 lane-contiguous
//            4 KB passes (1 KB per wave-store). No hot logic in the loop (R4/R7
//            post-mortem: inline logic + strided/churned address patterns cost 8-27%).
//   grid.sync()
//   phase 2: first 16384 threads scatter the 1.0f elements (one 4B store each).
//
// Flat layout (float32), NTOT = 1 + 2*N1 = 134217729:
//   p = 0 -> scalar 0.0; p in [1,1+N1) -> one-hot (j = p-1); p in [1+N1,1+2N1) -> same.
// One at p = 1 + o*N1 + g*2^25 + i*8192 + ((i&15)<<9 | i>>4) for o,g in {0,1}, i<4096.
// Tail float p = 134217728 is always 0 (hot <= 7935 < 8191).

typedef float floatx4 __attribute__((ext_vector_type(4)));

#define NBLK   2048u
#define QPB    16384u           // quads per block (256 KB contiguous)

__global__ void __launch_bounds__(256) rr_gate_coop(floatx4* __restrict__ out4,
                                                    float* __restrict__ out) {
    const unsigned tid = threadIdx.x;

    // ---- phase 1: pure contiguous zero-fill ----
    floatx4* base = out4 + (size_t)blockIdx.x * QPB + tid;
    const floatx4 z = (floatx4)(0.0f);
#pragma unroll 8
    for (unsigned m = 0; m < 64u; ++m) {
        base[(size_t)m * 256u] = z;
    }
    if (blockIdx.x == 0 && tid == 0) {
        out[134217728u] = 0.0f;     // final odd element, always 0
    }

    cg::this_grid().sync();

    // ---- phase 2: scatter the 16384 ones ----
    const unsigned t = blockIdx.x * 256u + tid;
    if (t < 16384u) {
        const unsigned i   = t & 4095u;        // token row
        const unsigned g   = (t >> 12) & 1u;   // group
        const unsigned o   = t >> 13;          // which of the two identical outputs
        const unsigned hot = ((i & 15u) << 9) | (i >> 4);
        const unsigned p   = 1u + o * 67108864u + g * 33554432u + i * 8192u + hot;
        out[p] = 1.0f;
    }
}

extern "C" void kernel_launch(void* const* d_in, const int* in_sizes, int n_in,
                              void* d_out, int out_size, void* d_ws, size_t ws_size,
                              hipStream_t stream) {
    (void)d_in; (void)in_sizes; (void)n_in; (void)d_ws; (void)ws_size; (void)out_size;
    floatx4* p4 = (floatx4*)d_out;
    float*   pf = (float*)d_out;
    void* args[] = {&p4, &pf};
    hipLaunchCooperativeKernel((const void*)rr_gate_coop, dim3(NBLK), dim3(256),
                               args, 0, stream);
}

// Round 9
// 95.607 us; speedup vs baseline: 4.1696x; 4.1696x over previous
//
#include <hip/hip_runtime.h>

// RoundRobinGate: output = (0.0 scalar, one-hot [2,4096,16,512] f32, same tensor as
// bool->f32). Fully input-independent: 537 MB of zeros + 16,384 ones. Pure store-BW.
//
// R9 hypothesis: rocclr fillBufferAligned hits 6.6-6.85 TB/s at ~10.5% occupancy
// (~256 blocks); all our slower kernels ran 8 blocks/CU. For pure store streams a few
// waves/CU saturate the store path; more waves add write-arbitration contention.
// -> exact fill shape at 256 blocks x 256 threads (1 block/CU), grid-stride 1 MB,
//    lane-contiguous plain float4 stores, branchless hot substitution (wave-uniform
//    SALU hot math; ~9 VALU per iteration vs ~375-cycle store budget).
//
// Flat layout (float32), NTOT = 1 + 2*N1 = 134217729:
//   p = 0 -> scalar 0.0; p in [1,1+N1) -> one-hot (j=p-1); p in [1+N1,1+2N1) -> same.
// Span r (= p>>13, 16384 spans of 8192 floats): span element 0 is never hot
// (hot <= 7935 < 8191); row r's hot sits at span offset hl = hot+1 with i = r & 4095,
// hot = ((i&15)<<9)|(i>>4). Grid stride = 65536 quads = 32 spans exactly, so
// ql = t & 2047 is loop-invariant and r advances by a uniform +32 per iteration.
// Waves (64-aligned) never straddle a span (2048-quad aligned) -> hot math is SALU.
// Tail float p = 134217728 (row 16383 offset 8191) is never hot -> 0.0 (thread 0).

typedef float floatx4 __attribute__((ext_vector_type(4)));

#define NBLK  256u
#define NTHR  (NBLK * 256u)     // 65536 threads; 33554432 quads / NTHR = 512 iters

__global__ void __launch_bounds__(256) rr_gate_fill(floatx4* __restrict__ out4,
                                                    float* __restrict__ out) {
    const unsigned t   = blockIdx.x * 256u + threadIdx.x;
    const unsigned el0 = (t & 2047u) << 2;  // span-element idx of component 0 (invariant)
    unsigned r         = t >> 11;           // span id (wave-uniform), +32 per iter
    floatx4* p         = out4 + t;

#pragma unroll 8
    for (unsigned it = 0; it < 512u; ++it) {
        const unsigned i  = r & 4095u;                          // token row   (SALU)
        const unsigned hl = (((i & 15u) << 9) | (i >> 4)) + 1u; // hot span-off (SALU)
        const unsigned d  = hl - el0;                           // per-thread
        floatx4 v;
        v.x = (d == 0u) ? 1.0f : 0.0f;
        v.y = (d == 1u) ? 1.0f : 0.0f;
        v.z = (d == 2u) ? 1.0f : 0.0f;
        v.w = (d == 3u) ? 1.0f : 0.0f;
        *p = v;
        p += NTHR;
        r += 32u;
    }
    // Final odd element (index 134217728): always 0.
    if (t == 0) {
        out[134217728u] = 0.0f;
    }
}

extern "C" void kernel_launch(void* const* d_in, const int* in_sizes, int n_in,
                              void* d_out, int out_size, void* d_ws, size_t ws_size,
                              hipStream_t stream) {
    (void)d_in; (void)in_sizes; (void)n_in; (void)d_ws; (void)ws_size; (void)out_size;
    hipLaunchKernelGGL(rr_gate_fill, dim3(NBLK), dim3(256), 0, stream,
                       (floatx4*)d_out, (float*)d_out);
}